// Round 2
// baseline (2370.968 us; speedup 1.0000x reference)
//
#include <hip/hip_runtime.h>
#include <cfloat>
#include <cstdint>

#define F_FEAT 256
#define NHID 128
#define NCLASS 16
#define KTOP 5

#define BR 128
#define BC 128
#define BKK 32
#define NSPLIT 16
#define QCAP 448

// ---------------- helpers ----------------
__device__ __forceinline__ void topk_insert5(float (&v)[5], int (&ix)[5], float cv, int ci) {
  // rank order: (value desc, index asc)  -- matches jax.lax.top_k
  if (cv < v[4] || (cv == v[4] && ci > ix[4])) return;
  int pos = 0;
#pragma unroll
  for (int j = 0; j < 5; ++j) pos += ((v[j] > cv) || (v[j] == cv && ix[j] < ci)) ? 1 : 0;
  if (pos >= 5) return;
  for (int j = 4; j > pos; --j) { v[j] = v[j - 1]; ix[j] = ix[j - 1]; }
  v[pos] = cv; ix[pos] = ci;
}

// ---------------- graph prep ----------------
__global__ void k_deg_count(const int* __restrict__ ar, const float* __restrict__ av,
                            const int* __restrict__ nr, const float* __restrict__ nv,
                            float* deg_adj, float* deg_ned, int* cntA, int* cntN, int E) {
  int e = blockIdx.x * blockDim.x + threadIdx.x;
  if (e >= E) return;
  int ra = ar[e]; int rn = nr[e];
  atomicAdd(&deg_adj[ra], av[e]);
  atomicAdd(&deg_ned[rn], nv[e]);
  atomicAdd(&cntA[ra], 1);
  atomicAdd(&cntN[rn], 1);
}

__global__ __launch_bounds__(1024) void k_scan_pair(const int* c0, int* o0, const int* c1, int* o1, int n) {
  const int* c = (blockIdx.x == 0) ? c0 : c1;
  int* o = (blockIdx.x == 0) ? o0 : o1;
  if (c == nullptr) return;
  __shared__ int buf[1024];
  int tid = threadIdx.x;
  int base = 0;
  int chunks = (n + 1023) >> 10;
  for (int ch = 0; ch < chunks; ++ch) {
    int i = (ch << 10) + tid;
    buf[tid] = (i < n) ? c[i] : 0;
    __syncthreads();
    for (int offd = 1; offd < 1024; offd <<= 1) {
      int t = (tid >= offd) ? buf[tid - offd] : 0;
      __syncthreads();
      buf[tid] += t;
      __syncthreads();
    }
    if (i < n) o[i + 1] = base + buf[tid];
    int tot = buf[1023];
    __syncthreads();
    base += tot;
  }
  if (tid == 0) o[0] = 0;
}

__global__ void k_rs(const float* deg_adj, const float* deg_ned, float* rs_adj, float* rinv_ned, int N) {
  int i = blockIdx.x * blockDim.x + threadIdx.x;
  if (i >= N) return;
  rs_adj[i] = 1.0f / (sqrtf(deg_adj[i]) + 1e-10f);
  rinv_ned[i] = 1.0f / (deg_ned[i] + 1e-10f);
}

__global__ void k_fill2(const int* ar, const int* nr, const int* rpA, const int* rpN,
                        int* fillA, int* fillN, int* permA, int* permN, int E) {
  int e = blockIdx.x * blockDim.x + threadIdx.x;
  if (e >= E) return;
  int ra = ar[e];
  permA[rpA[ra] + atomicAdd(&fillA[ra], 1)] = e;
  int rn = nr[e];
  permN[rpN[rn] + atomicAdd(&fillN[rn], 1)] = e;
}

__global__ void k_edgeval(const int* ar, const int* ac, const float* av,
                          const int* nr, const float* nv,
                          const float* rs_adj, const float* rinv_ned,
                          float* adj_sym, float* ned_rw, int E) {
  int e = blockIdx.x * blockDim.x + threadIdx.x;
  if (e >= E) return;
  adj_sym[e] = av[e] * rs_adj[ar[e]] * rs_adj[ac[e]];
  ned_rw[e] = nv[e] * rinv_ned[nr[e]];
}

// ---------------- SpMMs (CSR, block per row, feature per thread) ----------------
__global__ void k_spmm1(const int* __restrict__ rpA, const int* __restrict__ permA,
                        const int* __restrict__ ac, const float* __restrict__ adj_sym,
                        const float* __restrict__ x, const float* __restrict__ Wd1,
                        float* __restrict__ emb, int N) {
  int r = blockIdx.x; int f = threadIdx.x;
  int s = rpA[r], e = rpA[r + 1];
  float acc = 0.f;
  for (int i = s; i < e; ++i) {
    int id = permA[i];
    acc += adj_sym[id] * x[(size_t)ac[id] * F_FEAT + f];
  }
  emb[(size_t)r * F_FEAT + f] = tanhf(acc * Wd1[f]);
}

__global__ void k_spmm2_norm(const int* __restrict__ rpA, const int* __restrict__ permA,
                             const int* __restrict__ ac, const float* __restrict__ adj_sym,
                             const float* __restrict__ emb, const float* __restrict__ Wd2,
                             float* __restrict__ embn, int N) {
  __shared__ float red[F_FEAT];
  int r = blockIdx.x; int f = threadIdx.x;
  int s = rpA[r], e = rpA[r + 1];
  float acc = 0.f;
  for (int i = s; i < e; ++i) {
    int id = permA[i];
    acc += adj_sym[id] * emb[(size_t)ac[id] * F_FEAT + f];
  }
  float val = acc * Wd2[f];
  red[f] = val * val;
  __syncthreads();
  for (int st = F_FEAT / 2; st > 0; st >>= 1) {
    if (f < st) red[f] += red[f + st];
    __syncthreads();
  }
  float rinv = 1.0f / (sqrtf(red[0]) + 1e-12f);
  embn[(size_t)r * F_FEAT + f] = val * rinv;
}

__global__ void k_spmmT(const int* __restrict__ rpN, const int* __restrict__ permN,
                        const int* __restrict__ nc, const float* __restrict__ ned_rw,
                        const float* __restrict__ embn, float* __restrict__ Tm, int N) {
  int r = blockIdx.x; int f = threadIdx.x;
  int s = rpN[r], e = rpN[r + 1];
  float acc = 0.f;
  for (int i = s; i < e; ++i) {
    int id = permN[i];
    acc += ned_rw[id] * embn[(size_t)nc[id] * F_FEAT + f];
  }
  Tm[(size_t)r * F_FEAT + f] = acc;
}

// ---------------- transpose N x 256 -> 256 x N ----------------
__global__ void k_transpose(const float* __restrict__ in, float* __restrict__ out, int N) {
  __shared__ float tb[64][65];
  int r0 = blockIdx.x * 64;
  int c0 = blockIdx.y * 64;
  int tid = threadIdx.x;
  int rr = tid >> 4;
  int c4 = tid & 15;
#pragma unroll
  for (int i = 0; i < 4; ++i) {
    int r = rr + i * 16;
    int gr = r0 + r;
    float4 v = make_float4(0.f, 0.f, 0.f, 0.f);
    if (gr < N) v = *reinterpret_cast<const float4*>(in + (size_t)gr * F_FEAT + c0 + c4 * 4);
    tb[r][c4 * 4 + 0] = v.x; tb[r][c4 * 4 + 1] = v.y; tb[r][c4 * 4 + 2] = v.z; tb[r][c4 * 4 + 3] = v.w;
  }
  __syncthreads();
  int cc = tid >> 4;
  int r4 = tid & 15;
#pragma unroll
  for (int i = 0; i < 4; ++i) {
    int c = cc + i * 16;
    int gr = r0 + r4 * 4;
    if (gr < N) {
      float4 v;
      v.x = tb[r4 * 4 + 0][c]; v.y = tb[r4 * 4 + 1][c];
      v.z = tb[r4 * 4 + 2][c]; v.w = tb[r4 * 4 + 3][c];
      *reinterpret_cast<float4*>(out + (size_t)(c0 + c) * N + gr) = v;
    }
  }
}

// ---------------- fused dense GEMM (T @ embn^T) + per-row top-5 ----------------
__global__ __launch_bounds__(256, 2) void k_gemm_topk(
    const float* __restrict__ AT,   // 256 x N (k-major T)
    const float* __restrict__ BT,   // 256 x N (k-major embn)
    float* __restrict__ pv, int* __restrict__ pi,
    int N, int colTiles) {
  __shared__ float smem[2 * BKK * BR];     // A tile + B tile (also reused as scan buffer)
  float* sA = smem;
  float* sB = smem + BKK * BR;
  __shared__ float thr[BR];
  __shared__ float qv[QCAP];
  __shared__ unsigned qm[QCAP];
  __shared__ int qcnt;

  int tid = threadIdx.x;
  int tx = tid & 15, ty = tid >> 4;
  int lane = tid & 63;
  int row0 = blockIdx.x * BR;
  int per = (colTiles + NSPLIT - 1) / NSPLIT;
  int ct0 = blockIdx.y * per;
  int ct1 = min(ct0 + per, colTiles);

  float bv[5]; int bi[5];
#pragma unroll
  for (int k = 0; k < 5; ++k) { bv[k] = -FLT_MAX; bi[k] = 0x7fffffff; }
  if (tid < BR) thr[tid] = -FLT_MAX;
  if (tid == 0) qcnt = 0;
  __syncthreads();

  for (int ct = ct0; ct < ct1; ++ct) {
    int col0 = ct * BC;
    float acc[8][8];
#pragma unroll
    for (int a = 0; a < 8; ++a)
#pragma unroll
      for (int b = 0; b < 8; ++b) acc[a][b] = 0.f;

    for (int kc = 0; kc < F_FEAT; kc += BKK) {
      int f4 = tid & 31;
      int kk0 = tid >> 5;
#pragma unroll
      for (int j = 0; j < 4; ++j) {
        int kk = kk0 + j * 8;
        int k = kc + kk;
        int ga = row0 + f4 * 4;
        int gb = col0 + f4 * 4;
        float4 a4 = make_float4(0.f, 0.f, 0.f, 0.f);
        float4 b4 = make_float4(0.f, 0.f, 0.f, 0.f);
        if (ga < N) a4 = *reinterpret_cast<const float4*>(AT + (size_t)k * N + ga);
        if (gb < N) b4 = *reinterpret_cast<const float4*>(BT + (size_t)k * N + gb);
        *reinterpret_cast<float4*>(&sA[kk * BR + f4 * 4]) = a4;
        *reinterpret_cast<float4*>(&sB[kk * BC + f4 * 4]) = b4;
      }
      __syncthreads();
#pragma unroll 4
      for (int kk = 0; kk < BKK; ++kk) {
        float4 a0 = *reinterpret_cast<const float4*>(&sA[kk * BR + ty * 8]);
        float4 a1 = *reinterpret_cast<const float4*>(&sA[kk * BR + ty * 8 + 4]);
        float4 b0 = *reinterpret_cast<const float4*>(&sB[kk * BC + tx * 8]);
        float4 b1 = *reinterpret_cast<const float4*>(&sB[kk * BC + tx * 8 + 4]);
        float av8[8] = {a0.x, a0.y, a0.z, a0.w, a1.x, a1.y, a1.z, a1.w};
        float bv8[8] = {b0.x, b0.y, b0.z, b0.w, b1.x, b1.y, b1.z, b1.w};
#pragma unroll
        for (int a = 0; a < 8; ++a)
#pragma unroll
          for (int b = 0; b < 8; ++b) acc[a][b] += av8[a] * bv8[b];
      }
      __syncthreads();
    }

    bool first = (ct == ct0);
    if (!first) {
      float tr[8]; bool rok[8];
#pragma unroll
      for (int a = 0; a < 8; ++a) { tr[a] = thr[ty * 8 + a]; rok[a] = (row0 + ty * 8 + a) < N; }
#pragma unroll
      for (int a = 0; a < 8; ++a) {
#pragma unroll
        for (int b = 0; b < 8; ++b) {
          int c = col0 + tx * 8 + b;
          bool p = rok[a] && (c < N) && (acc[a][b] >= tr[a]);
          unsigned long long mk = __ballot(p);
          if (mk != 0ull) {
            int leader = __ffsll((long long)mk) - 1;
            int base = 0;
            if (lane == leader) base = atomicAdd(&qcnt, __popcll(mk));
            base = __shfl(base, leader, 64);
            if (p) {
              int pos = base + __popcll(mk & ((1ull << lane) - 1ull));
              if (pos < QCAP) {
                qv[pos] = acc[a][b];
                qm[pos] = ((unsigned)c << 7) | (unsigned)(ty * 8 + a);
              }
            }
          }
        }
      }
    }
    __syncthreads();
    int qn = qcnt;
    bool fullscan = first || (qn > QCAP);
    if (!fullscan) {
      if (tid < BR) {
        for (int i = 0; i < qn; ++i) {
          unsigned m = qm[i];
          if ((int)(m & 127u) == tid) topk_insert5(bv, bi, qv[i], (int)(m >> 7));
        }
      }
    } else {
      // 4 passes of 32 rows through smem scan buffer [32][132]
      for (int p = 0; p < 4; ++p) {
        __syncthreads();
        if ((ty >> 2) == p) {
          int rl = (ty & 3) * 8;
#pragma unroll
          for (int a = 0; a < 8; ++a) {
            float* dst = &smem[(rl + a) * 132 + tx * 8];
            dst[0] = acc[a][0]; dst[1] = acc[a][1]; dst[2] = acc[a][2]; dst[3] = acc[a][3];
            dst[4] = acc[a][4]; dst[5] = acc[a][5]; dst[6] = acc[a][6]; dst[7] = acc[a][7];
          }
        }
        __syncthreads();
        int rloc = tid - 32 * p;
        if (rloc >= 0 && rloc < 32) {
          for (int cdx = 0; cdx < BC; ++cdx) {
            int gc = col0 + cdx;
            if (gc < N) topk_insert5(bv, bi, smem[rloc * 132 + cdx], gc);
          }
        }
      }
      __syncthreads();
    }
    __syncthreads();
    if (tid < BR) thr[tid] = bv[4];
    if (tid == 0) qcnt = 0;
    __syncthreads();
  }

  if (tid < BR) {
    int r = row0 + tid;
    if (r < N) {
      size_t baseo = ((size_t)r * NSPLIT + blockIdx.y) * 5;
#pragma unroll
      for (int k = 0; k < 5; ++k) { pv[baseo + k] = bv[k]; pi[baseo + k] = bi[k]; }
    }
  }
}

// ---------------- merge partial top-5, build new degrees/counts ----------------
__global__ void k_merge(const float* __restrict__ pv, const int* __restrict__ pi,
                        float* __restrict__ topv, int* __restrict__ topi,
                        const float* deg_adj, float* deg_new, const int* cntA, int* cnt_new, int N) {
  int r = blockIdx.x * blockDim.x + threadIdx.x;
  if (r >= N) return;
  float v[5]; int ix[5];
#pragma unroll
  for (int k = 0; k < 5; ++k) { v[k] = -FLT_MAX; ix[k] = 0x7fffffff; }
  size_t base = (size_t)r * NSPLIT * 5;
  for (int s = 0; s < NSPLIT; ++s)
    for (int k = 0; k < 5; ++k)
      topk_insert5(v, ix, pv[base + s * 5 + k], pi[base + s * 5 + k]);
  float sumv = 0.f;
  for (int k = 0; k < 5; ++k) {
    topv[(size_t)r * 5 + k] = v[k];
    topi[(size_t)r * 5 + k] = ix[k];
    sumv += v[k];
    atomicAdd(&deg_new[ix[k]], v[k]);
    atomicAdd(&cnt_new[ix[k]], 1);
  }
  atomicAdd(&deg_new[r], deg_adj[r] + sumv);
  atomicAdd(&cnt_new[r], cntA[r] + KTOP);
}

__global__ void k_rs_new(const float* deg_new, float* rs_new, int N) {
  int i = blockIdx.x * blockDim.x + threadIdx.x;
  if (i >= N) return;
  rs_new[i] = 1.0f / (sqrtf(deg_new[i]) + 1e-10f);
}

__global__ void k_fill_new(const int* ar, const int* topi, const int* rp_new, int* fill_new,
                           int* perm_new, int E, int NK, int total) {
  int t = blockIdx.x * blockDim.x + threadIdx.x;
  if (t >= total) return;
  int r;
  if (t < E) r = ar[t];
  else if (t < E + NK) r = (t - E) / KTOP;
  else r = topi[t - E - NK];
  perm_new[rp_new[r] + atomicAdd(&fill_new[r], 1)] = t;
}

// ---------------- dense layers ----------------
__global__ void k_xw1(const float* __restrict__ x, const float* __restrict__ W1,
                      float* __restrict__ XW1, int N) {
  int c = threadIdx.x & 127;
  int half = threadIdx.x >> 7;
  int r0 = blockIdx.x * 8 + half * 4;
  int rm = N - 1;
  const float* x0 = x + (size_t)min(r0 + 0, rm) * F_FEAT;
  const float* x1 = x + (size_t)min(r0 + 1, rm) * F_FEAT;
  const float* x2 = x + (size_t)min(r0 + 2, rm) * F_FEAT;
  const float* x3 = x + (size_t)min(r0 + 3, rm) * F_FEAT;
  float a0 = 0.f, a1 = 0.f, a2 = 0.f, a3 = 0.f;
  for (int k = 0; k < F_FEAT; ++k) {
    float wv = W1[k * NHID + c];
    a0 += x0[k] * wv; a1 += x1[k] * wv; a2 += x2[k] * wv; a3 += x3[k] * wv;
  }
  if (r0 + 0 < N) XW1[(size_t)(r0 + 0) * NHID + c] = a0;
  if (r0 + 1 < N) XW1[(size_t)(r0 + 1) * NHID + c] = a1;
  if (r0 + 2 < N) XW1[(size_t)(r0 + 2) * NHID + c] = a2;
  if (r0 + 3 < N) XW1[(size_t)(r0 + 3) * NHID + c] = a3;
}

__global__ void k_spmm_h(const int* __restrict__ rp, const int* __restrict__ perm,
                         const int* __restrict__ ac, const float* __restrict__ av,
                         const int* __restrict__ topi, const float* __restrict__ topv,
                         const float* __restrict__ rs, const float* __restrict__ XW1,
                         const float* __restrict__ b1, float* __restrict__ h,
                         int N, int E, int NK) {
  int r = blockIdx.x; int f = threadIdx.x;  // 128 threads
  int s = rp[r], e = rp[r + 1];
  float acc = 0.f;
  for (int i = s; i < e; ++i) {
    int id = perm[i];
    int c; float v;
    if (id < E) { c = ac[id]; v = av[id]; }
    else if (id < E + NK) { int q = id - E; c = topi[q]; v = topv[q]; }
    else { int q = id - E - NK; c = q / KTOP; v = topv[q]; }
    acc += v * rs[c] * XW1[(size_t)c * NHID + f];
  }
  float o = rs[r] * acc + b1[f];
  h[(size_t)r * NHID + f] = fmaxf(o, 0.f);
}

__global__ void k_hw2(const float* __restrict__ h, const float* __restrict__ W2,
                      float* __restrict__ HW2, int N) {
  int tid = threadIdx.x;
  int rr = tid >> 4, c = tid & 15;
  int r = blockIdx.x * 16 + rr;
  if (r >= N) return;
  float acc = 0.f;
  for (int k = 0; k < NHID; ++k) acc += h[(size_t)r * NHID + k] * W2[k * NCLASS + c];
  HW2[(size_t)r * NCLASS + c] = acc;
}

__global__ void k_spmm_out(const int* __restrict__ rp, const int* __restrict__ perm,
                           const int* __restrict__ ac, const float* __restrict__ av,
                           const int* __restrict__ topi, const float* __restrict__ topv,
                           const float* __restrict__ rs, const float* __restrict__ HW2,
                           const float* __restrict__ b2, float* __restrict__ out,
                           int N, int E, int NK) {
  int tid = threadIdx.x;
  int rr = tid >> 4, c = tid & 15;
  int r = blockIdx.x * 16 + rr;
  if (r >= N) return;
  int s = rp[r], e = rp[r + 1];
  float acc = 0.f;
  for (int i = s; i < e; ++i) {
    int id = perm[i];
    int cc; float v;
    if (id < E) { cc = ac[id]; v = av[id]; }
    else if (id < E + NK) { int q = id - E; cc = topi[q]; v = topv[q]; }
    else { int q = id - E - NK; cc = q / KTOP; v = topv[q]; }
    acc += v * rs[cc] * HW2[(size_t)cc * NCLASS + c];
  }
  out[(size_t)r * NCLASS + c] = rs[r] * acc + b2[c];
}

// ---------------- host ----------------
extern "C" void kernel_launch(void* const* d_in, const int* in_sizes, int n_in,
                              void* d_out, int out_size, void* d_ws, size_t ws_size,
                              hipStream_t stream) {
  (void)n_in; (void)out_size; (void)ws_size;
  const float* x   = (const float*)d_in[0];
  const int*   ar  = (const int*)d_in[1];
  const int*   ac  = (const int*)d_in[2];
  const float* av  = (const float*)d_in[3];
  const int*   nr  = (const int*)d_in[4];
  const int*   nc  = (const int*)d_in[5];
  const float* nv  = (const float*)d_in[6];
  const float* Wd1 = (const float*)d_in[7];
  const float* Wd2 = (const float*)d_in[8];
  const float* W1  = (const float*)d_in[9];
  const float* b1  = (const float*)d_in[10];
  const float* W2  = (const float*)d_in[11];
  const float* b2  = (const float*)d_in[12];
  int N = in_sizes[0] / F_FEAT;
  int E = in_sizes[3];
  int NK = N * KTOP;
  int total_new = E + 2 * NK;

  char* w = (char*)d_ws;
  size_t off = 0;
  auto carve = [&](size_t elems) -> void* {
    void* p = (void*)(w + off);
    off += (elems * 4 + 255) & ~((size_t)255);
    return p;
  };
  size_t zstart = off;
  float* deg_adj = (float*)carve(N);
  float* deg_ned = (float*)carve(N);
  float* deg_new = (float*)carve(N);
  int* cntA = (int*)carve(N);
  int* cntN = (int*)carve(N);
  int* cnt_new = (int*)carve(N);
  int* fillA = (int*)carve(N);
  int* fillN = (int*)carve(N);
  int* fill_new = (int*)carve(N);
  size_t zbytes = off - zstart;
  float* rs_adj = (float*)carve(N);
  float* rinv_ned = (float*)carve(N);
  float* rs_new = (float*)carve(N);
  float* adj_sym = (float*)carve(E);
  float* ned_rw = (float*)carve(E);
  int* rpA = (int*)carve(N + 1);
  int* rpN = (int*)carve(N + 1);
  int* rp_new = (int*)carve(N + 1);
  int* permA = (int*)carve(E);
  int* permN = (int*)carve(E);
  int* perm_new = (int*)carve(total_new);
  float* emb  = (float*)carve((size_t)N * F_FEAT);
  float* embn = (float*)carve((size_t)N * F_FEAT);
  float* Tm   = (float*)carve((size_t)N * F_FEAT);
  float* topv = (float*)carve(NK);
  int*   topi = (int*)carve(NK);
  float* pv = (float*)carve((size_t)N * NSPLIT * 5);
  int*   pi = (int*)carve((size_t)N * NSPLIT * 5);
  float* XW1  = (float*)carve((size_t)N * NHID);
  float* hbuf = (float*)carve((size_t)N * NHID);
  float* HW2  = (float*)carve((size_t)N * NCLASS);
  float* TT   = emb;   // reuse: emb dead after spmm2
  float* embT = Tm;    // reuse: Tm dead after its transpose

  hipMemsetAsync(w + zstart, 0, zbytes, stream);

  int eb = (E + 255) / 256;
  k_deg_count<<<eb, 256, 0, stream>>>(ar, av, nr, nv, deg_adj, deg_ned, cntA, cntN, E);
  k_scan_pair<<<2, 1024, 0, stream>>>(cntA, rpA, cntN, rpN, N);
  k_rs<<<(N + 255) / 256, 256, 0, stream>>>(deg_adj, deg_ned, rs_adj, rinv_ned, N);
  k_fill2<<<eb, 256, 0, stream>>>(ar, nr, rpA, rpN, fillA, fillN, permA, permN, E);
  k_edgeval<<<eb, 256, 0, stream>>>(ar, ac, av, nr, nv, rs_adj, rinv_ned, adj_sym, ned_rw, E);
  k_spmm1<<<N, F_FEAT, 0, stream>>>(rpA, permA, ac, adj_sym, x, Wd1, emb, N);
  k_spmm2_norm<<<N, F_FEAT, 0, stream>>>(rpA, permA, ac, adj_sym, emb, Wd2, embn, N);
  k_spmmT<<<N, F_FEAT, 0, stream>>>(rpN, permN, nc, ned_rw, embn, Tm, N);
  dim3 tg((N + 63) / 64, 4);
  k_transpose<<<tg, 256, 0, stream>>>(Tm, TT, N);
  k_transpose<<<tg, 256, 0, stream>>>(embn, embT, N);
  int colTiles = (N + BC - 1) / BC;
  dim3 gg((N + BR - 1) / BR, NSPLIT);
  k_gemm_topk<<<gg, 256, 0, stream>>>(TT, embT, pv, pi, N, colTiles);
  k_merge<<<(N + 255) / 256, 256, 0, stream>>>(pv, pi, topv, topi, deg_adj, deg_new, cntA, cnt_new, N);
  k_scan_pair<<<1, 1024, 0, stream>>>(cnt_new, rp_new, nullptr, nullptr, N);
  k_rs_new<<<(N + 255) / 256, 256, 0, stream>>>(deg_new, rs_new, N);
  k_fill_new<<<(total_new + 255) / 256, 256, 0, stream>>>(ar, topi, rp_new, fill_new, perm_new, E, NK, total_new);
  k_xw1<<<(N + 7) / 8, 256, 0, stream>>>(x, W1, XW1, N);
  k_spmm_h<<<N, NHID, 0, stream>>>(rp_new, perm_new, ac, av, topi, topv, rs_new, XW1, b1, hbuf, N, E, NK);
  k_hw2<<<(N + 15) / 16, 256, 0, stream>>>(hbuf, W2, HW2, N);
  k_spmm_out<<<(N + 15) / 16, 256, 0, stream>>>(rp_new, perm_new, ac, av, topi, topv, rs_new, HW2, b2, (float*)d_out, N, E, NK);
}